// Round 5
// baseline (857.557 us; speedup 1.0000x reference)
//
#include <hip/hip_runtime.h>
#include <math.h>

#define B_   64
#define N_   512
#define C_   128
#define FS_  16
#define RES_ 511

__device__ __forceinline__ float bf2f(unsigned short u) {
  union { unsigned int i; float f; } v;
  v.i = ((unsigned int)u) << 16;
  return v.f;
}

// dtype sniff: bf16 N(0,1) data -> ~100% of ushorts have exponent in [100,140];
// f32 data read as ushorts -> ~58% (mantissa halves are random).
__device__ __forceinline__ int detect16(const unsigned short* p) {
  int sane = 0;
  for (int i = 0; i < 64; ++i) {
    int e = (p[i] >> 7) & 0xFF;
    if (e >= 100 && e <= 140) sane++;
  }
  return (sane >= 48) ? 0 : 1;   // 0 = bf16 storage, 1 = f32 storage
}

__device__ __forceinline__ float2 ld2(const void* p, int idx, int mode) {
  if (mode) return ((const float2*)p)[idx];
  ushort2 u = ((const ushort2*)p)[idx];
  return make_float2(bf2f(u.x), bf2f(u.y));
}
__device__ __forceinline__ float ld1(const void* p, int idx, int mode) {
  if (mode) return ((const float*)p)[idx];
  return bf2f(((const unsigned short*)p)[idx]);
}

// wave-wide f64 butterfly sum; result identical in all 64 lanes
__device__ __forceinline__ double wred(double v) {
#pragma unroll
  for (int m = 32; m; m >>= 1) v += __shfl_xor(v, m, 64);
  return v;
}

__global__ __launch_bounds__(512) void k_all(
    const void* __restrict__ x, const void* __restrict__ w,
    const void* __restrict__ a, const int* __restrict__ ep,
    float* __restrict__ out)
{
  __shared__ float sc[N_];    // score by original node idx
  __shared__ float asr[N_];   // x . a_src by original idx
  __shared__ float ads[N_];   // x . a_dst by original idx
  __shared__ float svv[N_];   // sort working values
  __shared__ int   si[N_];    // sort working indices -> order
  __shared__ float srk[N_];   // tanh(sorted score)
  __shared__ float wrw[RES_];
  __shared__ int   jmp[RES_];

  const int bb = blockIdx.x;
  const int t = threadIdx.x, lane = t & 63, wvid = t >> 6;   // 8 waves

  const int mode_x = detect16((const unsigned short*)x);
  const int mode_w = detect16((const unsigned short*)w);
  const int mode_a = detect16((const unsigned short*)a);

  // epoch: int32, or f32 bits, fallback 10
  int ei = ep[0];
  float evv;
  if (ei >= 0 && ei <= 1000000) evv = (float)ei;
  else {
    union { int i; float f; } u; u.i = ei; evv = u.f;
    if (!(evv >= 0.f && evv <= 1e6f)) evv = 10.f;
  }
  const double tau64 = 10.0 * pow(0.01, (double)evv / 100.0);
  const float tau32 = (float)tau64;

  // hoisted weights: lane covers channels 2*lane, 2*lane+1
  const float2 wv2 = ld2(w, lane, mode_w);
  const float2 sv2 = ld2(a, lane, mode_a);
  const float2 dv2 = ld2(a, 64 + lane, mode_a);

  const double nww = wred((double)wv2.x * wv2.x + (double)wv2.y * wv2.y);
  const float nrm32 = (float)sqrt(nww);

  // ---- phase 1: per-node dots (f64 accumulate, f32 round at op boundary) --
  for (int node = wvid; node < N_; node += 8) {
    float2 xv = ld2(x, (bb * N_ + node) * 64 + lane, mode_x);
    double s  = wred((double)xv.x * wv2.x + (double)xv.y * wv2.y);
    double da = wred((double)xv.x * sv2.x + (double)xv.y * sv2.y);
    double dd = wred((double)xv.x * dv2.x + (double)xv.y * dv2.y);
    if (lane == 0) {
      sc[node]  = ((float)s) / nrm32;     // f32 divide, like np
      asr[node] = (float)da;
      ads[node] = (float)dd;
    }
  }
  __syncthreads();

  // ---- phase 2: stable descending bitonic sort of (score, idx) -----------
  svv[t] = sc[t];
  si[t]  = t;
  __syncthreads();
  for (int k = 2; k <= N_; k <<= 1) {
    for (int j = k >> 1; j > 0; j >>= 1) {
      int ixj = t ^ j;
      if (ixj > t) {
        float av = svv[t], bv = svv[ixj];
        int   ai = si[t],  bi = si[ixj];
        bool up = ((t & k) == 0);
        bool sw = up ? (bv > av || (bv == av && bi < ai))
                     : (av > bv || (av == bv && ai < bi));
        if (sw) { svv[t] = bv; si[t] = bi; svv[ixj] = av; si[ixj] = ai; }
      }
      __syncthreads();
    }
  }
  srk[t] = tanhf(svv[t]);
  __syncthreads();

  // ---- phase 3: window attention -> w_row, jumps --------------------------
  for (int r = wvid; r < RES_; r += 8) {
    int o_r = si[r];
    float2 xs = ld2(x, (bb * N_ + o_r) * 64 + lane, mode_x);
    float asr_r = asr[o_r];
    float kk[FS_], aa[FS_];
#pragma unroll
    for (int j = 0; j < FS_; ++j) {
      int dest = r + j;
      if (dest < N_) {
        int o_d = si[dest];
        float2 xd = ld2(x, (bb * N_ + o_d) * 64 + lane, mode_x);
        float dx = xs.x - xd.x, dy = xs.y - xd.y;   // f32 subtract, like np
        float qx = dx * dx,     qy = dy * dy;       // f32 square, like np
        double s2 = wred((double)qx + (double)qy);  // f64 sum
        float d32 = (float)sqrt(s2);
        kk[j] = (float)exp((double)d32 * -0.5) - 1e-20f;
        aa[j] = asr_r + ads[o_d];
      } else {
        kk[j] = -1e-20f;
        aa[j] = -1e9f;
      }
    }
    float tt[FS_];
    float mx = -INFINITY;
#pragma unroll
    for (int j = 0; j < FS_; ++j) { tt[j] = aa[j] / tau32; mx = fmaxf(mx, tt[j]); }
    float ee[FS_];
    double ssum = 0.0;
#pragma unroll
    for (int j = 0; j < FS_; ++j) { ee[j] = (float)exp((double)(tt[j] - mx)); ssum += ee[j]; }
    float s32 = (float)ssum;
    float wr = -INFINITY, best = -INFINITY;
    int bj = 1;
#pragma unroll
    for (int j = 0; j < FS_; ++j) {
      float q  = kk[j] * (ee[j] / s32);             // f32 div then f32 mul, like np
      float qm = (r + j < N_) ? q : -1e9f;
      if (qm > wr) wr = qm;                          // max over all j
      if (j >= 1 && qm > best) { best = qm; bj = j; }// first argmax over j>=1
    }
    if (lane == 0) { wrw[r] = wr; jmp[r] = bj; }
  }
  __syncthreads();

  // ---- phase 4: sequential jump-chain pooling (np scan order) -------------
  if (t < C_) {
    float acc = 0.f;
    int p = 0;
    while (p < RES_) {
      float wvv = wrw[p] * srk[p];
      float xc  = ld1(x, (bb * N_ + si[p]) * C_ + t, mode_x);
      acc = acc + wvv * xc;
      p += jmp[p];
    }
    out[bb * C_ + t] = acc;   // output read as f32 (established R3/R4)
  }
}

extern "C" void kernel_launch(void* const* d_in, const int* in_sizes, int n_in,
                              void* d_out, int out_size, void* d_ws, size_t ws_size,
                              hipStream_t stream) {
  const void* x = nullptr; const void* w = nullptr; const void* a = nullptr;
  const int* ep = nullptr;
  for (int i = 0; i < n_in; ++i) {
    int s = in_sizes[i];
    if      (s == B_ * N_ * C_) x  = d_in[i];
    else if (s == C_)           w  = d_in[i];
    else if (s == 2 * C_)       a  = d_in[i];
    else if (s == 1)            ep = (const int*)d_in[i];
  }
  if (!x)  x  = d_in[0];
  if (!w)  w  = d_in[2];
  if (!a)  a  = d_in[3];
  if (!ep) ep = (const int*)d_in[4];
  (void)out_size; (void)d_ws; (void)ws_size;

  k_all<<<B_, 512, 0, stream>>>(x, w, a, ep, (float*)d_out);
}

// Round 6
// 275.532 us; speedup vs baseline: 3.1124x; 3.1124x over previous
//
#include <hip/hip_runtime.h>
#include <math.h>

#define B_   64
#define N_   512
#define C_   128
#define FS_  16
#define RES_ 511

__device__ __forceinline__ float bf2f(unsigned short u) {
  union { unsigned int i; float f; } v;
  v.i = ((unsigned int)u) << 16;
  return v.f;
}

// dtype sniff: bf16 N(0,1) data -> ~100% of ushorts have exponent in [100,140];
// f32 data read as ushorts -> ~58% (mantissa halves random).
__device__ __forceinline__ int detect16(const unsigned short* p) {
  int sane = 0;
  for (int i = 0; i < 64; ++i) {
    int e = (p[i] >> 7) & 0xFF;
    if (e >= 100 && e <= 140) sane++;
  }
  return (sane >= 48) ? 0 : 1;   // 0 = bf16 storage, 1 = f32 storage
}

__device__ __forceinline__ float2 ld2(const void* p, int idx, int mode) {
  if (mode) return ((const float2*)p)[idx];
  ushort2 u = ((const ushort2*)p)[idx];
  return make_float2(bf2f(u.x), bf2f(u.y));
}
__device__ __forceinline__ float ld1(const void* p, int idx, int mode) {
  if (mode) return ((const float*)p)[idx];
  return bf2f(((const unsigned short*)p)[idx]);
}

// wave-wide f64 butterfly sum; result identical in all 64 lanes
__device__ __forceinline__ double wred(double v) {
#pragma unroll
  for (int m = 32; m; m >>= 1) v += __shfl_xor(v, m, 64);
  return v;
}

// ---------------- Kernel 0: dtype flags (once) ----------------------------
__global__ void k_detect(const unsigned short* __restrict__ x,
                         const unsigned short* __restrict__ w,
                         const unsigned short* __restrict__ a,
                         int* __restrict__ flag) {
  if (threadIdx.x == 0) {
    flag[0] = detect16(x);
    flag[1] = detect16(w);
    flag[2] = detect16(a);
  }
}

// ---------------- Kernel A: per-node dots (one wave per node) -------------
__global__ __launch_bounds__(256) void k_scores(
    const void* __restrict__ x, const void* __restrict__ w,
    const void* __restrict__ a, const int* __restrict__ flag,
    float* __restrict__ sc, float* __restrict__ asr, float* __restrict__ ads)
{
  const int mode_x = flag[0], mode_w = flag[1], mode_a = flag[2];
  const int gid  = blockIdx.x * blockDim.x + threadIdx.x;
  const int wid  = gid >> 6;            // global node index, < B_*N_
  const int lane = threadIdx.x & 63;    // covers channels 2*lane, 2*lane+1

  const float2 wv2 = ld2(w, lane, mode_w);
  const float2 sv2 = ld2(a, lane, mode_a);
  const float2 dv2 = ld2(a, 64 + lane, mode_a);
  const double nww = wred((double)wv2.x * wv2.x + (double)wv2.y * wv2.y);
  const float nrm32 = (float)sqrt(nww);

  float2 xv = ld2(x, wid * 64 + lane, mode_x);
  double s  = wred((double)xv.x * wv2.x + (double)xv.y * wv2.y);
  double da = wred((double)xv.x * sv2.x + (double)xv.y * sv2.y);
  double dd = wred((double)xv.x * dv2.x + (double)xv.y * dv2.y);
  if (lane == 0) {
    sc[wid]  = ((float)s) / nrm32;      // f32 divide, like np
    asr[wid] = (float)da;
    ads[wid] = (float)dd;
  }
}

// ---------------- Kernel B: stable descending bitonic sort per batch ------
__global__ __launch_bounds__(512) void k_sort(
    const float* __restrict__ sc, int* __restrict__ order,
    float* __restrict__ srk)
{
  __shared__ float svv[N_];
  __shared__ int   si[N_];
  const int b = blockIdx.x, t = threadIdx.x;
  svv[t] = sc[b * N_ + t];
  si[t]  = t;
  __syncthreads();
  for (int k = 2; k <= N_; k <<= 1) {
    for (int j = k >> 1; j > 0; j >>= 1) {
      int ixj = t ^ j;
      if (ixj > t) {
        float av = svv[t], bv = svv[ixj];
        int   ai = si[t],  bi = si[ixj];
        bool up = ((t & k) == 0);
        bool sw = up ? (bv > av || (bv == av && bi < ai))
                     : (av > bv || (av == bv && ai < bi));
        if (sw) { svv[t] = bv; si[t] = bi; svv[ixj] = av; si[ixj] = ai; }
      }
      __syncthreads();
    }
  }
  order[b * N_ + t] = si[t];
  srk[b * N_ + t]   = tanhf(svv[t]);
}

// ---------------- Kernel C: window attention (one wave per (b,r)) ---------
__global__ __launch_bounds__(256) void k_att(
    const void* __restrict__ x, const float* __restrict__ asr,
    const float* __restrict__ ads, const int* __restrict__ order,
    const int* __restrict__ ep, const int* __restrict__ flag,
    float* __restrict__ wrw, int* __restrict__ jmp)
{
  const int mode_x = flag[0];
  const int gid  = blockIdx.x * blockDim.x + threadIdx.x;
  const int wid  = gid >> 6;            // < B_*RES_ (grid exact)
  const int lane = threadIdx.x & 63;
  const int b = wid / RES_;
  const int r = wid - b * RES_;
  const int* ob = order + b * N_;

  // epoch: int32, or f32 bits, fallback 10
  int ei = ep[0];
  float evv;
  if (ei >= 0 && ei <= 1000000) evv = (float)ei;
  else {
    union { int i; float f; } u; u.i = ei; evv = u.f;
    if (!(evv >= 0.f && evv <= 1e6f)) evv = 10.f;
  }
  const float tau32 = (float)(10.0 * pow(0.01, (double)evv / 100.0));

  const int o_r = ob[r];
  const float2 xs = ld2(x, (b * N_ + o_r) * 64 + lane, mode_x);
  const float asr_r = asr[b * N_ + o_r];

  float kk[FS_], aa[FS_];
#pragma unroll
  for (int j = 0; j < FS_; ++j) {
    int dest = r + j;
    if (dest < N_) {
      int o_d = ob[dest];
      float2 xd = ld2(x, (b * N_ + o_d) * 64 + lane, mode_x);
      float dx = xs.x - xd.x, dy = xs.y - xd.y;   // f32 subtract, like np
      float qx = dx * dx,     qy = dy * dy;       // f32 square, like np
      double s2 = wred((double)qx + (double)qy);  // f64 sum
      float d32 = (float)sqrt(s2);
      kk[j] = (float)exp((double)d32 * -0.5) - 1e-20f;
      aa[j] = asr_r + ads[b * N_ + o_d];
    } else {
      kk[j] = -1e-20f;
      aa[j] = -1e9f;
    }
  }
  float tt[FS_];
  float mx = -INFINITY;
#pragma unroll
  for (int j = 0; j < FS_; ++j) { tt[j] = aa[j] / tau32; mx = fmaxf(mx, tt[j]); }
  float ee[FS_];
  double ssum = 0.0;
#pragma unroll
  for (int j = 0; j < FS_; ++j) { ee[j] = (float)exp((double)(tt[j] - mx)); ssum += ee[j]; }
  float s32 = (float)ssum;
  float wr = -INFINITY, best = -INFINITY;
  int bj = 1;
#pragma unroll
  for (int j = 0; j < FS_; ++j) {
    float q  = kk[j] * (ee[j] / s32);              // f32 div, f32 mul, like np
    float qm = (r + j < N_) ? q : -1e9f;
    if (qm > wr) wr = qm;                          // max over all j
    if (j >= 1 && qm > best) { best = qm; bj = j; }// first argmax over j>=1
  }
  if (lane == 0) {
    wrw[b * N_ + r] = wr;
    jmp[b * N_ + r] = bj;
  }
}

// ---------------- Kernel D: sequential jump-chain pooling -----------------
__global__ __launch_bounds__(128) void k_chain(
    const void* __restrict__ x, const float* __restrict__ wrw,
    const float* __restrict__ srk, const int* __restrict__ jmp,
    const int* __restrict__ order, const int* __restrict__ flag,
    float* __restrict__ out)
{
  __shared__ float wl[RES_];
  __shared__ float sl[RES_];
  __shared__ int   jl[RES_];
  __shared__ int   ol[N_];
  const int mode_x = flag[0];
  const int b = blockIdx.x, t = threadIdx.x;   // t in [0,128)
  for (int r = t; r < N_; r += C_) {
    ol[r] = order[b * N_ + r];
    if (r < RES_) {
      wl[r] = wrw[b * N_ + r];
      sl[r] = srk[b * N_ + r];
      jl[r] = jmp[b * N_ + r];
    }
  }
  __syncthreads();
  float acc = 0.f;
  int p = 0;
  while (p < RES_) {
    float wvv = wl[p] * sl[p];
    float xc  = ld1(x, (b * N_ + ol[p]) * C_ + t, mode_x);
    acc = acc + wvv * xc;
    p += jl[p];
  }
  out[b * C_ + t] = acc;
}

extern "C" void kernel_launch(void* const* d_in, const int* in_sizes, int n_in,
                              void* d_out, int out_size, void* d_ws, size_t ws_size,
                              hipStream_t stream) {
  const void* x = nullptr; const void* w = nullptr; const void* a = nullptr;
  const int* ep = nullptr;
  for (int i = 0; i < n_in; ++i) {
    int s = in_sizes[i];
    if      (s == B_ * N_ * C_) x  = d_in[i];
    else if (s == C_)           w  = d_in[i];
    else if (s == 2 * C_)       a  = d_in[i];
    else if (s == 1)            ep = (const int*)d_in[i];
  }
  if (!x)  x  = d_in[0];
  if (!w)  w  = d_in[2];
  if (!a)  a  = d_in[3];
  if (!ep) ep = (const int*)d_in[4];
  (void)out_size; (void)ws_size;

  float* ws = (float*)d_ws;
  const int NN = B_ * N_;              // 32768
  float* sc    = ws;                   // NN
  float* asr   = ws + NN;              // NN
  float* ads   = ws + 2 * NN;          // NN
  int*   order = (int*)(ws + 3 * NN);  // NN
  float* srk   = ws + 4 * NN;          // NN
  float* wrw   = ws + 5 * NN;          // NN
  int*   jmp   = (int*)(ws + 6 * NN);  // NN
  int*   flag  = (int*)(ws + 7 * NN);  // 4

  k_detect<<<1, 64, 0, stream>>>((const unsigned short*)x,
                                 (const unsigned short*)w,
                                 (const unsigned short*)a, flag);
  k_scores<<<NN / 4, 256, 0, stream>>>(x, w, a, flag, sc, asr, ads);
  k_sort<<<B_, N_, 0, stream>>>(sc, order, srk);
  k_att<<<(B_ * RES_) / 4, 256, 0, stream>>>(x, asr, ads, order, ep, flag, wrw, jmp);
  k_chain<<<B_, C_, 0, stream>>>(x, wrw, srk, jmp, order, flag, (float*)d_out);
}

// Round 7
// 240.342 us; speedup vs baseline: 3.5681x; 1.1464x over previous
//
#include <hip/hip_runtime.h>
#include <math.h>

#define B_   64
#define N_   512
#define C_   128
#define FS_  16
#define RES_ 511

__device__ __forceinline__ float bf2f(unsigned short u) {
  union { unsigned int i; float f; } v;
  v.i = ((unsigned int)u) << 16;
  return v.f;
}

// dtype sniff: bf16 N(0,1) data -> ~100% of ushorts have exponent in [100,140];
// f32 data read as ushorts -> ~58% (mantissa halves random).
__device__ __forceinline__ int detect16(const unsigned short* p) {
  int sane = 0;
  for (int i = 0; i < 64; ++i) {
    int e = (p[i] >> 7) & 0xFF;
    if (e >= 100 && e <= 140) sane++;
  }
  return (sane >= 48) ? 0 : 1;   // 0 = bf16 storage, 1 = f32 storage
}

__device__ __forceinline__ float2 ld2(const void* p, int idx, int mode) {
  if (mode) return ((const float2*)p)[idx];
  ushort2 u = ((const ushort2*)p)[idx];
  return make_float2(bf2f(u.x), bf2f(u.y));
}
__device__ __forceinline__ float ld1(const void* p, int idx, int mode) {
  if (mode) return ((const float*)p)[idx];
  return bf2f(((const unsigned short*)p)[idx]);
}

// wave-wide f64 butterfly sum; result identical in all 64 lanes
__device__ __forceinline__ double wred(double v) {
#pragma unroll
  for (int m = 32; m; m >>= 1) v += __shfl_xor(v, m, 64);
  return v;
}

__device__ __forceinline__ float get_epoch(const int* ep) {
  int ei = ep[0];
  if (ei >= 0 && ei <= 1000000) return (float)ei;
  union { int i; float f; } u; u.i = ei;
  return (u.f >= 0.f && u.f <= 1e6f) ? u.f : 10.f;
}

// ---------------- Kernel A: per-node dots (one wave per node) -------------
// f64 reductions kept: these feed the argsort (proven rank-flip fragile).
__global__ __launch_bounds__(256) void k_scores(
    const void* __restrict__ x, const void* __restrict__ w,
    const void* __restrict__ a,
    float* __restrict__ sc, float* __restrict__ asr, float* __restrict__ ads)
{
  const int mode_x = detect16((const unsigned short*)x);
  const int mode_w = detect16((const unsigned short*)w);
  const int mode_a = detect16((const unsigned short*)a);
  const int gid  = blockIdx.x * blockDim.x + threadIdx.x;
  const int wid  = gid >> 6;            // global node index, < B_*N_
  const int lane = threadIdx.x & 63;    // covers channels 2*lane, 2*lane+1

  const float2 wv2 = ld2(w, lane, mode_w);
  const float2 sv2 = ld2(a, lane, mode_a);
  const float2 dv2 = ld2(a, 64 + lane, mode_a);
  const double nww = wred((double)wv2.x * wv2.x + (double)wv2.y * wv2.y);
  const float nrm32 = (float)sqrt(nww);

  float2 xv = ld2(x, wid * 64 + lane, mode_x);
  double s  = wred((double)xv.x * wv2.x + (double)xv.y * wv2.y);
  double da = wred((double)xv.x * sv2.x + (double)xv.y * sv2.y);
  double dd = wred((double)xv.x * dv2.x + (double)xv.y * dv2.y);
  if (lane == 0) {
    sc[wid]  = ((float)s) / nrm32;      // f32 divide, like np
    asr[wid] = (float)da;
    ads[wid] = (float)dd;
  }
}

// ---------------- Kernel B: stable descending bitonic sort per batch ------
__global__ __launch_bounds__(512) void k_sort(
    const float* __restrict__ sc, int* __restrict__ order,
    float* __restrict__ srk)
{
  __shared__ float svv[N_];
  __shared__ int   si[N_];
  const int b = blockIdx.x, t = threadIdx.x;
  svv[t] = sc[b * N_ + t];
  si[t]  = t;
  __syncthreads();
  for (int k = 2; k <= N_; k <<= 1) {
    for (int j = k >> 1; j > 0; j >>= 1) {
      int ixj = t ^ j;
      if (ixj > t) {
        float av = svv[t], bv = svv[ixj];
        int   ai = si[t],  bi = si[ixj];
        bool up = ((t & k) == 0);
        bool sw = up ? (bv > av || (bv == av && bi < ai))
                     : (av > bv || (av == bv && ai < bi));
        if (sw) { svv[t] = bv; si[t] = bi; svv[ixj] = av; si[ixj] = ai; }
      }
      __syncthreads();
    }
  }
  order[b * N_ + t] = si[t];
  srk[b * N_ + t]   = tanhf(svv[t]);
}

// ---------------- Kernel C: window attention (one wave per (b,r)) ---------
// f64 only for the cross-lane distance sum; all scalar math f32.
__global__ __launch_bounds__(256) void k_att(
    const void* __restrict__ x, const float* __restrict__ asr,
    const float* __restrict__ ads, const int* __restrict__ order,
    const int* __restrict__ ep,
    float* __restrict__ wrw, int* __restrict__ jmp)
{
  const int mode_x = detect16((const unsigned short*)x);
  const int gid  = blockIdx.x * blockDim.x + threadIdx.x;
  const int wid  = gid >> 6;            // < B_*RES_ (grid exact)
  const int lane = threadIdx.x & 63;
  const int b = wid / RES_;
  const int r = wid - b * RES_;
  const int* ob = order + b * N_;

  const float evv = get_epoch(ep);
  const float tau32 = (float)(10.0 * pow(0.01, (double)evv / 100.0));
  const float inv_tau = 1.0f / tau32;

  const int o_r = ob[r];
  const float2 xs = ld2(x, (b * N_ + o_r) * 64 + lane, mode_x);
  const float asr_r = asr[b * N_ + o_r];

  float kk[FS_], aa[FS_];
#pragma unroll
  for (int j = 0; j < FS_; ++j) {
    int dest = r + j;
    if (dest < N_) {
      int o_d = ob[dest];
      float2 xd = ld2(x, (b * N_ + o_d) * 64 + lane, mode_x);
      float dx = xs.x - xd.x, dy = xs.y - xd.y;   // f32 subtract, like np
      float qx = dx * dx,     qy = dy * dy;       // f32 square, like np
      double s2 = wred((double)qx + (double)qy);  // f64 cross-lane sum
      float d32 = sqrtf((float)s2);
      kk[j] = __expf(-0.5f * d32) - 1e-20f;
      aa[j] = asr_r + ads[b * N_ + o_d];
    } else {
      kk[j] = -1e-20f;
      aa[j] = -1e9f;
    }
  }
  float tt[FS_];
  float mx = -INFINITY;
#pragma unroll
  for (int j = 0; j < FS_; ++j) { tt[j] = aa[j] * inv_tau; mx = fmaxf(mx, tt[j]); }
  float ee[FS_];
  float ssum = 0.0f;
#pragma unroll
  for (int j = 0; j < FS_; ++j) { ee[j] = __expf(tt[j] - mx); ssum += ee[j]; }
  float sinv = 1.0f / ssum;
  float wr = -INFINITY, best = -INFINITY;
  int bj = 1;
#pragma unroll
  for (int j = 0; j < FS_; ++j) {
    float q  = kk[j] * (ee[j] * sinv);
    float qm = (r + j < N_) ? q : -1e9f;
    if (qm > wr) wr = qm;                          // max over all j
    if (j >= 1 && qm > best) { best = qm; bj = j; }// first argmax over j>=1
  }
  if (lane == 0) {
    wrw[b * N_ + r] = wr;
    jmp[b * N_ + r] = bj;
  }
}

// ---------------- Kernel D: jump-chain pooling via pointer doubling -------
// Path nodes are strictly increasing, so f^t(0) for t=0..P-1 enumerates the
// path in order; entries saturate to sentinel 511 past the end. Accumulation
// is done per-channel in exact path order (bit-identical to the serial scan).
__global__ __launch_bounds__(512) void k_chain(
    const void* __restrict__ x, const float* __restrict__ wrw,
    const float* __restrict__ srk, const int* __restrict__ jmp,
    const int* __restrict__ order, float* __restrict__ out)
{
  __shared__ int   tab[9][N_];   // f^(2^k) jump tables, sentinel 511
  __shared__ int   ol[N_];       // order
  __shared__ float wl[N_];       // wrw
  __shared__ float sl2[N_];      // srk
  __shared__ float cl[N_];       // coeff list in path order
  __shared__ int   rl[N_];       // row-id list (original node index)
  __shared__ int   Pcnt;

  const int mode_x = detect16((const unsigned short*)x);
  const int b = blockIdx.x, t = threadIdx.x;     // 512 threads

  ol[t] = order[b * N_ + t];
  if (t < RES_) {
    wl[t]  = wrw[b * N_ + t];
    sl2[t] = srk[b * N_ + t];
    tab[0][t] = min(t + jmp[b * N_ + t], RES_);  // cap at sentinel 511
  } else {
    tab[0][t] = RES_;                            // tab[k][511] = 511
  }
  if (t == 0) Pcnt = RES_;
  __syncthreads();
#pragma unroll
  for (int k = 1; k < 9; ++k) {
    int v = tab[k - 1][tab[k - 1][t]];
    __syncthreads();        // tab[k-1] reads done before writing tab[k]? different arrays — barrier orders the NEXT round's reads
    tab[k][t] = v;
    __syncthreads();
  }
  // node = f^t(0): iterate composition over set bits of t (iterates commute)
  int node = 0;
#pragma unroll
  for (int k = 0; k < 9; ++k)
    if ((t >> k) & 1) node = tab[k][node];
  bool valid = (node < RES_);
  cl[t] = valid ? wl[node] * sl2[node] : 0.0f;
  rl[t] = valid ? ol[node] : 0;                  // row 0 with coeff 0: safe no-op
  if (!valid) atomicMin(&Pcnt, t);               // P = first invalid t (prefix)
  __syncthreads();

  if (t < C_) {
    const int P = Pcnt;
    float acc = 0.f;
    int i = 0;
    for (; i + 4 <= P; i += 4) {                 // 4-wide: overlap global loads
      float c0 = cl[i],     c1 = cl[i + 1], c2 = cl[i + 2], c3 = cl[i + 3];
      int   r0 = rl[i],     r1 = rl[i + 1], r2 = rl[i + 2], r3 = rl[i + 3];
      float x0 = ld1(x, (b * N_ + r0) * C_ + t, mode_x);
      float x1 = ld1(x, (b * N_ + r1) * C_ + t, mode_x);
      float x2 = ld1(x, (b * N_ + r2) * C_ + t, mode_x);
      float x3 = ld1(x, (b * N_ + r3) * C_ + t, mode_x);
      acc = acc + c0 * x0;                       // exact reference order
      acc = acc + c1 * x1;
      acc = acc + c2 * x2;
      acc = acc + c3 * x3;
    }
    for (; i < P; ++i)
      acc = acc + cl[i] * ld1(x, (b * N_ + rl[i]) * C_ + t, mode_x);
    out[b * C_ + t] = acc;
  }
}

extern "C" void kernel_launch(void* const* d_in, const int* in_sizes, int n_in,
                              void* d_out, int out_size, void* d_ws, size_t ws_size,
                              hipStream_t stream) {
  const void* x = nullptr; const void* w = nullptr; const void* a = nullptr;
  const int* ep = nullptr;
  for (int i = 0; i < n_in; ++i) {
    int s = in_sizes[i];
    if      (s == B_ * N_ * C_) x  = d_in[i];
    else if (s == C_)           w  = d_in[i];
    else if (s == 2 * C_)       a  = d_in[i];
    else if (s == 1)            ep = (const int*)d_in[i];
  }
  if (!x)  x  = d_in[0];
  if (!w)  w  = d_in[2];
  if (!a)  a  = d_in[3];
  if (!ep) ep = (const int*)d_in[4];
  (void)out_size; (void)ws_size;

  float* ws = (float*)d_ws;
  const int NN = B_ * N_;              // 32768
  float* sc    = ws;                   // NN
  float* asr   = ws + NN;              // NN
  float* ads   = ws + 2 * NN;          // NN
  int*   order = (int*)(ws + 3 * NN);  // NN
  float* srk   = ws + 4 * NN;          // NN
  float* wrw   = ws + 5 * NN;          // NN
  int*   jmp   = (int*)(ws + 6 * NN);  // NN

  k_scores<<<NN / 4, 256, 0, stream>>>(x, w, a, sc, asr, ads);
  k_sort<<<B_, N_, 0, stream>>>(sc, order, srk);
  k_att<<<(B_ * RES_) / 4, 256, 0, stream>>>(x, asr, ads, order, ep, wrw, jmp);
  k_chain<<<B_, N_, 0, stream>>>(x, wrw, srk, jmp, order, (float*)d_out);
}

// Round 8
// 159.178 us; speedup vs baseline: 5.3874x; 1.5099x over previous
//
#include <hip/hip_runtime.h>
#include <math.h>

#define B_   64
#define N_   512
#define C_   128
#define FS_  16
#define RES_ 511

__device__ __forceinline__ float bf2f(unsigned short u) {
  union { unsigned int i; float f; } v;
  v.i = ((unsigned int)u) << 16;
  return v.f;
}

// dtype sniff: bf16 N(0,1) data -> ~100% of ushorts have exponent in [100,140];
// f32 data read as ushorts -> ~58% (mantissa halves random).
__device__ __forceinline__ int detect16(const unsigned short* p) {
  int sane = 0;
  for (int i = 0; i < 64; ++i) {
    int e = (p[i] >> 7) & 0xFF;
    if (e >= 100 && e <= 140) sane++;
  }
  return (sane >= 48) ? 0 : 1;   // 0 = bf16 storage, 1 = f32 storage
}

__device__ __forceinline__ float2 ld2(const void* p, int idx, int mode) {
  if (mode) return ((const float2*)p)[idx];
  ushort2 u = ((const ushort2*)p)[idx];
  return make_float2(bf2f(u.x), bf2f(u.y));
}
__device__ __forceinline__ float ld1(const void* p, int idx, int mode) {
  if (mode) return ((const float*)p)[idx];
  return bf2f(((const unsigned short*)p)[idx]);
}
// idx4 counts float4/ushort4 chunks (4 elements)
__device__ __forceinline__ float4 ld4(const void* p, int idx4, int mode) {
  if (mode) return ((const float4*)p)[idx4];
  ushort4 u = ((const ushort4*)p)[idx4];
  return make_float4(bf2f(u.x), bf2f(u.y), bf2f(u.z), bf2f(u.w));
}

// wave-wide f64 butterfly sum; identical in all 64 lanes
__device__ __forceinline__ double wred(double v) {
#pragma unroll
  for (int m = 32; m; m >>= 1) v += __shfl_xor(v, m, 64);
  return v;
}

__device__ __forceinline__ float get_epoch(const int* ep) {
  int ei = ep[0];
  if (ei >= 0 && ei <= 1000000) return (float)ei;
  union { int i; float f; } u; u.i = ei;
  return (u.f >= 0.f && u.f <= 1e6f) ? u.f : 10.f;
}

// ---------------- Kernel 0: setup (flags, tau, |w|) once ------------------
__global__ void k_setup(const unsigned short* __restrict__ x,
                        const unsigned short* __restrict__ w,
                        const unsigned short* __restrict__ a,
                        const int* __restrict__ ep,
                        int* __restrict__ imeta, float* __restrict__ fmeta) {
  __shared__ int s_fw;
  const int lane = threadIdx.x;
  if (lane == 0) {
    imeta[0] = detect16(x);
    int fw = detect16(w);
    imeta[1] = fw;
    imeta[2] = detect16(a);
    s_fw = fw;
    float evv = get_epoch(ep);
    fmeta[0] = (float)(10.0 * pow(0.01, (double)evv / 100.0));   // tau
  }
  __syncthreads();
  const float2 wv2 = ld2(w, lane, s_fw);
  const double nww = wred((double)wv2.x * wv2.x + (double)wv2.y * wv2.y);
  if (lane == 0) fmeta[1] = (float)sqrt(nww);                    // |w| (f32)
}

// ---------------- Kernel A: per-node dots (one wave per node) -------------
// f64 reductions kept: these feed the argsort (proven rank-flip fragile).
__global__ __launch_bounds__(256) void k_scores(
    const void* __restrict__ x, const void* __restrict__ w,
    const void* __restrict__ a, const int* __restrict__ imeta,
    const float* __restrict__ fmeta,
    float* __restrict__ sc, float* __restrict__ asr, float* __restrict__ ads)
{
  const int mode_x = imeta[0], mode_w = imeta[1], mode_a = imeta[2];
  const float nrm32 = fmeta[1];
  const int gid  = blockIdx.x * blockDim.x + threadIdx.x;
  const int wid  = gid >> 6;            // global node index, < B_*N_
  const int lane = threadIdx.x & 63;    // covers channels 2*lane, 2*lane+1

  const float2 wv2 = ld2(w, lane, mode_w);
  const float2 sv2 = ld2(a, lane, mode_a);
  const float2 dv2 = ld2(a, 64 + lane, mode_a);

  float2 xv = ld2(x, wid * 64 + lane, mode_x);
  double s  = wred((double)xv.x * wv2.x + (double)xv.y * wv2.y);
  double da = wred((double)xv.x * sv2.x + (double)xv.y * sv2.y);
  double dd = wred((double)xv.x * dv2.x + (double)xv.y * dv2.y);
  if (lane == 0) {
    sc[wid]  = ((float)s) / nrm32;      // f32 divide, like np
    asr[wid] = (float)da;
    ads[wid] = (float)dd;
  }
}

// ---------------- Kernel B: stable descending rank sort per batch ---------
// rank(i) = #{k: sc[k] > sc[i]} + #{k < i: sc[k] == sc[i]}  (exact, stable)
__global__ __launch_bounds__(512) void k_sort(
    const float* __restrict__ sc, int* __restrict__ order,
    float* __restrict__ srk)
{
  __shared__ float sl[N_];
  const int b = blockIdx.x, t = threadIdx.x;
  const float my = sc[b * N_ + t];
  sl[t] = my;
  __syncthreads();
  int rank = 0;
#pragma unroll 8
  for (int k = 0; k < N_; ++k) {
    float v = sl[k];                    // LDS broadcast, conflict-free
    rank += (int)((v > my) || (v == my && k < t));
  }
  order[b * N_ + rank] = t;
  srk[b * N_ + rank]   = tanhf(my);
}

// ---------------- Kernel C: window attention (one wave per (b,r)) ---------
// lane = cg*16 + j : lane j owns neighbor j, cg = channel quarter.
__global__ __launch_bounds__(256) void k_att(
    const void* __restrict__ x, const float* __restrict__ asr,
    const float* __restrict__ ads, const int* __restrict__ order,
    const int* __restrict__ imeta, const float* __restrict__ fmeta,
    float* __restrict__ wrw, int* __restrict__ jmp)
{
  const int mode_x = imeta[0];
  const float inv_tau = 1.0f / fmeta[0];
  const int gid  = blockIdx.x * blockDim.x + threadIdx.x;
  const int wid  = gid >> 6;            // < B_*RES_ (grid exact)
  const int lane = threadIdx.x & 63;
  const int j  = lane & 15;             // neighbor offset
  const int cg = lane >> 4;             // channel quarter [0,4)
  const int b = wid / RES_;
  const int r = wid - b * RES_;
  const int* ob = order + b * N_;
  const int bN = b * N_;

  const int o_r = ob[r];
  const int dest = r + j;
  const bool valid = dest < N_;
  const int o_d = ob[valid ? dest : (N_ - 1)];

  // distance: f32 sub, f32 square (np semantics), exact f64 accumulation
  double dacc = 0.0;
  const int sbase = (bN + o_r) * (C_ / 4) + cg * 8;
  const int dbase = (bN + o_d) * (C_ / 4) + cg * 8;
#pragma unroll
  for (int c = 0; c < 8; ++c) {
    float4 s4 = ld4(x, sbase + c, mode_x);
    float4 d4 = ld4(x, dbase + c, mode_x);
    float e0 = s4.x - d4.x, e1 = s4.y - d4.y, e2 = s4.z - d4.z, e3 = s4.w - d4.w;
    float q0 = e0 * e0, q1 = e1 * e1, q2 = e2 * e2, q3 = e3 * e3;
    dacc += (double)q0; dacc += (double)q1; dacc += (double)q2; dacc += (double)q3;
  }
  dacc += __shfl_xor(dacc, 16, 64);     // reduce across channel quarters
  dacc += __shfl_xor(dacc, 32, 64);     // all lanes now hold full d^2 for their j

  const float asr_r = asr[bN + o_r];
  float d32 = sqrtf((float)dacc);
  float kkj = valid ? (__expf(-0.5f * d32) - 1e-20f) : -1e-20f;
  float aaj = valid ? (asr_r + ads[bN + o_d]) : -1e9f;
  float ttj = aaj * inv_tau;

  // softmax across the 16 j-lanes (groups identical, so 16-lane butterflies)
  float mx = ttj;
#pragma unroll
  for (int m = 1; m < 16; m <<= 1) mx = fmaxf(mx, __shfl_xor(mx, m, 64));
  float eej = __expf(ttj - mx);
  float ssum = eej;
#pragma unroll
  for (int m = 1; m < 16; m <<= 1) ssum += __shfl_xor(ssum, m, 64);
  float q  = kkj * (eej * (1.0f / ssum));
  float qm = valid ? q : -1e9f;

  float wr = qm;                         // max over all j
#pragma unroll
  for (int m = 1; m < 16; m <<= 1) wr = fmaxf(wr, __shfl_xor(wr, m, 64));
  float qe = (j == 0) ? -INFINITY : qm;  // exclude j=0 for the jump argmax
  float m1 = qe;
#pragma unroll
  for (int m = 1; m < 16; m <<= 1) m1 = fmaxf(m1, __shfl_xor(m1, m, 64));
  unsigned long long mask = __ballot(qe == m1);   // pattern replicated per group
  int bj = __builtin_ctz((unsigned)(mask & 0xFFFEu));  // first argmax, j>=1

  if (lane == 0) {
    wrw[bN + r] = wr;
    jmp[bN + r] = bj;                    // equals 1 + argmax(qm[1:])
  }
}

// ---------------- Kernel D: jump-chain pooling via pointer doubling -------
// Path nodes strictly increase; f^t(0) enumerates the path in order with
// sentinel 511. Accumulation per channel in exact reference scan order.
__global__ __launch_bounds__(512) void k_chain(
    const void* __restrict__ x, const float* __restrict__ wrw,
    const float* __restrict__ srk, const int* __restrict__ jmp,
    const int* __restrict__ order, const int* __restrict__ imeta,
    float* __restrict__ out)
{
  __shared__ int   tab[9][N_];   // f^(2^k) jump tables, sentinel 511
  __shared__ int   ol[N_];       // order
  __shared__ float wl[N_];       // wrw
  __shared__ float sl2[N_];      // srk
  __shared__ float cl[N_];       // coeff list in path order
  __shared__ int   rl[N_];       // row-id list (original node index)
  __shared__ int   Pcnt;

  const int mode_x = imeta[0];
  const int b = blockIdx.x, t = threadIdx.x;     // 512 threads

  ol[t] = order[b * N_ + t];
  if (t < RES_) {
    wl[t]  = wrw[b * N_ + t];
    sl2[t] = srk[b * N_ + t];
    tab[0][t] = min(t + jmp[b * N_ + t], RES_);  // cap at sentinel 511
  } else {
    tab[0][t] = RES_;                            // tab[k][511] = 511
  }
  if (t == 0) Pcnt = RES_;
  __syncthreads();
#pragma unroll
  for (int k = 1; k < 9; ++k) {
    int v = tab[k - 1][tab[k - 1][t]];
    tab[k][t] = v;
    __syncthreads();
  }
  // node = f^t(0): compose over set bits of t
  int node = 0;
#pragma unroll
  for (int k = 0; k < 9; ++k)
    if ((t >> k) & 1) node = tab[k][node];
  bool valid = (node < RES_);
  cl[t] = valid ? wl[node] * sl2[node] : 0.0f;
  rl[t] = valid ? ol[node] : 0;                  // coeff 0 -> safe no-op
  if (!valid) atomicMin(&Pcnt, t);               // P = first invalid t
  __syncthreads();

  if (t < C_) {
    const int P = Pcnt;
    float acc = 0.f;
    int i = 0;
    for (; i + 4 <= P; i += 4) {                 // 4-wide load overlap
      float c0 = cl[i],     c1 = cl[i + 1], c2 = cl[i + 2], c3 = cl[i + 3];
      int   r0 = rl[i],     r1 = rl[i + 1], r2 = rl[i + 2], r3 = rl[i + 3];
      float x0 = ld1(x, (b * N_ + r0) * C_ + t, mode_x);
      float x1 = ld1(x, (b * N_ + r1) * C_ + t, mode_x);
      float x2 = ld1(x, (b * N_ + r2) * C_ + t, mode_x);
      float x3 = ld1(x, (b * N_ + r3) * C_ + t, mode_x);
      acc = acc + c0 * x0;                       // exact reference order
      acc = acc + c1 * x1;
      acc = acc + c2 * x2;
      acc = acc + c3 * x3;
    }
    for (; i < P; ++i)
      acc = acc + cl[i] * ld1(x, (b * N_ + rl[i]) * C_ + t, mode_x);
    out[b * C_ + t] = acc;
  }
}

extern "C" void kernel_launch(void* const* d_in, const int* in_sizes, int n_in,
                              void* d_out, int out_size, void* d_ws, size_t ws_size,
                              hipStream_t stream) {
  const void* x = nullptr; const void* w = nullptr; const void* a = nullptr;
  const int* ep = nullptr;
  for (int i = 0; i < n_in; ++i) {
    int s = in_sizes[i];
    if      (s == B_ * N_ * C_) x  = d_in[i];
    else if (s == C_)           w  = d_in[i];
    else if (s == 2 * C_)       a  = d_in[i];
    else if (s == 1)            ep = (const int*)d_in[i];
  }
  if (!x)  x  = d_in[0];
  if (!w)  w  = d_in[2];
  if (!a)  a  = d_in[3];
  if (!ep) ep = (const int*)d_in[4];
  (void)out_size; (void)ws_size;

  float* ws = (float*)d_ws;
  const int NN = B_ * N_;              // 32768
  float* sc    = ws;                   // NN
  float* asr   = ws + NN;              // NN
  float* ads   = ws + 2 * NN;          // NN
  int*   order = (int*)(ws + 3 * NN);  // NN
  float* srk   = ws + 4 * NN;          // NN
  float* wrw   = ws + 5 * NN;          // NN
  int*   jmp   = (int*)(ws + 6 * NN);  // NN
  int*   imeta = (int*)(ws + 7 * NN);  // 3 ints
  float* fmeta = ws + 7 * NN + 8;      // tau, |w|

  k_setup<<<1, 64, 0, stream>>>((const unsigned short*)x,
                                (const unsigned short*)w,
                                (const unsigned short*)a, ep, imeta, fmeta);
  k_scores<<<NN / 4, 256, 0, stream>>>(x, w, a, imeta, fmeta, sc, asr, ads);
  k_sort<<<B_, N_, 0, stream>>>(sc, order, srk);
  k_att<<<(B_ * RES_) / 4, 256, 0, stream>>>(x, asr, ads, order, imeta, fmeta, wrw, jmp);
  k_chain<<<B_, N_, 0, stream>>>(x, wrw, srk, jmp, order, imeta, (float*)d_out);
}

// Round 9
// 145.134 us; speedup vs baseline: 5.9087x; 1.0968x over previous
//
#include <hip/hip_runtime.h>
#include <math.h>

#define B_   64
#define N_   512
#define C_   128
#define FS_  16
#define RES_ 511
#define CHUNK_ 64
#define HALO_  15
#define MAXR_  (CHUNK_ + HALO_)   // 79
#define RSTRIDE_ 132              // dwords per staged row (+4 pad)

__device__ __forceinline__ float bf2f(unsigned short u) {
  union { unsigned int i; float f; } v;
  v.i = ((unsigned int)u) << 16;
  return v.f;
}

// dtype sniff: bf16 N(0,1) data -> ~100% of ushorts have exponent in [100,140];
// f32 data read as ushorts -> ~58% (mantissa halves random).
__device__ __forceinline__ int detect16(const unsigned short* p) {
  int sane = 0;
  for (int i = 0; i < 64; ++i) {
    int e = (p[i] >> 7) & 0xFF;
    if (e >= 100 && e <= 140) sane++;
  }
  return (sane >= 48) ? 0 : 1;   // 0 = bf16 storage, 1 = f32 storage
}

__device__ __forceinline__ float2 ld2(const void* p, int idx, int mode) {
  if (mode) return ((const float2*)p)[idx];
  ushort2 u = ((const ushort2*)p)[idx];
  return make_float2(bf2f(u.x), bf2f(u.y));
}
__device__ __forceinline__ float ld1(const void* p, int idx, int mode) {
  if (mode) return ((const float*)p)[idx];
  return bf2f(((const unsigned short*)p)[idx]);
}
// idx4 counts 4-element chunks
__device__ __forceinline__ float4 ld4(const void* p, int idx4, int mode) {
  if (mode) return ((const float4*)p)[idx4];
  ushort4 u = ((const ushort4*)p)[idx4];
  return make_float4(bf2f(u.x), bf2f(u.y), bf2f(u.z), bf2f(u.w));
}

// wave-wide butterfly sums; identical in all 64 lanes
__device__ __forceinline__ double wred(double v) {
#pragma unroll
  for (int m = 32; m; m >>= 1) v += __shfl_xor(v, m, 64);
  return v;
}
__device__ __forceinline__ float wredf(float v) {
#pragma unroll
  for (int m = 32; m; m >>= 1) v += __shfl_xor(v, m, 64);
  return v;
}

__device__ __forceinline__ float get_epoch(const int* ep) {
  int ei = ep[0];
  if (ei >= 0 && ei <= 1000000) return (float)ei;
  union { int i; float f; } u; u.i = ei;
  return (u.f >= 0.f && u.f <= 1e6f) ? u.f : 10.f;
}

// ---------------- Kernel A: per-node dots (one wave per node) -------------
// sc keeps f64 (feeds argsort, proven rank-flip fragile); asr/ads f32
// (feed softmax where decision gaps are O(0.05)).
__global__ __launch_bounds__(256) void k_scores(
    const void* __restrict__ x, const void* __restrict__ w,
    const void* __restrict__ a,
    float* __restrict__ sc, float* __restrict__ asr, float* __restrict__ ads)
{
  __shared__ int s_modes[3];
  if (threadIdx.x == 0) {
    s_modes[0] = detect16((const unsigned short*)x);
    s_modes[1] = detect16((const unsigned short*)w);
    s_modes[2] = detect16((const unsigned short*)a);
  }
  __syncthreads();
  const int mode_x = s_modes[0], mode_w = s_modes[1], mode_a = s_modes[2];
  const int gid  = blockIdx.x * blockDim.x + threadIdx.x;
  const int wid  = gid >> 6;            // global node index, < B_*N_
  const int lane = threadIdx.x & 63;    // covers channels 2*lane, 2*lane+1

  const float2 wv2 = ld2(w, lane, mode_w);
  const float2 sv2 = ld2(a, lane, mode_a);
  const float2 dv2 = ld2(a, 64 + lane, mode_a);
  const double nww = wred((double)wv2.x * wv2.x + (double)wv2.y * wv2.y);
  const float nrm32 = (float)sqrt(nww);

  float2 xv = ld2(x, wid * 64 + lane, mode_x);
  double s  = wred((double)xv.x * wv2.x + (double)xv.y * wv2.y);
  float  da = wredf(xv.x * sv2.x + xv.y * sv2.y);
  float  dd = wredf(xv.x * dv2.x + xv.y * dv2.y);
  if (lane == 0) {
    sc[wid]  = ((float)s) / nrm32;      // f32 divide, like np
    asr[wid] = da;
    ads[wid] = dd;
  }
}

// ---------------- Kernel B: stable descending rank sort per batch ---------
// rank(i) = #{k: sc[k] > sc[i]} + #{k < i: sc[k] == sc[i]}  (exact, stable)
__global__ __launch_bounds__(512) void k_sort(
    const float* __restrict__ sc, int* __restrict__ order,
    float* __restrict__ srk)
{
  __shared__ float sl[N_];
  const int b = blockIdx.x, t = threadIdx.x;
  const float my = sc[b * N_ + t];
  sl[t] = my;
  __syncthreads();
  int rank = 0;
#pragma unroll 8
  for (int k = 0; k < N_; ++k) {
    float v = sl[k];                    // LDS broadcast, conflict-free
    rank += (int)((v > my) || (v == my && k < t));
  }
  order[b * N_ + rank] = t;
  srk[b * N_ + rank]   = tanhf(my);
}

// ---------------- Kernel C: LDS-staged window attention -------------------
// 512 blocks = 64 batches x 8 chunks of 64 r. Stage chunk rows (+15 halo)
// into LDS once, compute all pairs from LDS. lane = cg*16+j as in R8.
__global__ __launch_bounds__(256) void k_att(
    const void* __restrict__ x, const float* __restrict__ asr,
    const float* __restrict__ ads, const int* __restrict__ order,
    const int* __restrict__ ep,
    float* __restrict__ wrw, int* __restrict__ jmp)
{
  __shared__ float rows[MAXR_ * RSTRIDE_];   // 79*132*4 = 41712 B
  __shared__ float ads_l[MAXR_];
  __shared__ float asr_l[CHUNK_];
  __shared__ int   ord_l[MAXR_];
  __shared__ int   s_mode;
  __shared__ float s_invtau;

  const int blk = blockIdx.x;           // 64*8
  const int b = blk >> 3;
  const int cr0 = (blk & 7) * CHUNK_;
  const int bN = b * N_;
  const int t = threadIdx.x;
  const int nrows = min(N_ - cr0, MAXR_);

  if (t == 0) {
    s_mode = detect16((const unsigned short*)x);
    float evv = get_epoch(ep);
    s_invtau = (float)(1.0 / (10.0 * pow(0.01, (double)evv / 100.0)));
  }
  if (t < nrows) {
    int o = order[bN + cr0 + t];
    ord_l[t] = o;
    ads_l[t] = ads[bN + o];
    if (t < CHUNK_) asr_l[t] = asr[bN + o];
  }
  __syncthreads();
  const int mode = s_mode;
  const float inv_tau = s_invtau;

  // stage rows: 8 rows in flight, 32 threads x float4 per row (coalesced)
  {
    const int rl0 = t >> 5, c4 = t & 31;
    for (int rl = rl0; rl < nrows; rl += 8) {
      float4 v = ld4(x, (bN + ord_l[rl]) * 32 + c4, mode);
      float* dst = &rows[rl * RSTRIDE_ + c4 * 4];
      dst[0] = v.x; dst[1] = v.y; dst[2] = v.z; dst[3] = v.w;
    }
  }
  __syncthreads();

  const int lane = t & 63, wv = t >> 6;
  const int j = lane & 15, cg = lane >> 4;

  for (int ii = 0; ii < 16; ++ii) {
    const int rloc = wv * 16 + ii;
    const int r = cr0 + rloc;
    if (r >= RES_) break;               // trims only chunk-7 tail (wave-uniform)
    const int dest = r + j;
    const bool valid = dest < N_;
    const int dl = (valid ? dest : (N_ - 1)) - cr0;   // < nrows

    const float* srcp = &rows[rloc * RSTRIDE_ + cg * 32];
    const float* dstp = &rows[dl   * RSTRIDE_ + cg * 32];
    double dacc = 0.0;
#pragma unroll
    for (int c = 0; c < 8; ++c) {
      float4 s4 = *(const float4*)(srcp + c * 4);
      float4 d4 = *(const float4*)(dstp + c * 4);
      float e0 = s4.x - d4.x, e1 = s4.y - d4.y;
      float e2 = s4.z - d4.z, e3 = s4.w - d4.w;
      float q0 = e0 * e0, q1 = e1 * e1, q2 = e2 * e2, q3 = e3 * e3;
      dacc += (double)q0; dacc += (double)q1; dacc += (double)q2; dacc += (double)q3;
    }
    dacc += __shfl_xor(dacc, 16, 64);   // reduce across channel quarters
    dacc += __shfl_xor(dacc, 32, 64);

    float d32 = sqrtf((float)dacc);
    float kkj = valid ? (__expf(-0.5f * d32) - 1e-20f) : -1e-20f;
    float aaj = valid ? (asr_l[rloc] + ads_l[dl]) : -1e9f;
    float ttj = aaj * inv_tau;

    float mx = ttj;
#pragma unroll
    for (int m = 1; m < 16; m <<= 1) mx = fmaxf(mx, __shfl_xor(mx, m, 64));
    float eej = __expf(ttj - mx);
    float ssum = eej;
#pragma unroll
    for (int m = 1; m < 16; m <<= 1) ssum += __shfl_xor(ssum, m, 64);
    float q  = kkj * (eej * (1.0f / ssum));
    float qm = valid ? q : -1e9f;

    float wr = qm;                       // max over all j
#pragma unroll
    for (int m = 1; m < 16; m <<= 1) wr = fmaxf(wr, __shfl_xor(wr, m, 64));
    float qe = (j == 0) ? -INFINITY : qm;
    float m1 = qe;
#pragma unroll
    for (int m = 1; m < 16; m <<= 1) m1 = fmaxf(m1, __shfl_xor(m1, m, 64));
    unsigned long long mask = __ballot(qe == m1);
    int bj = __builtin_ctz((unsigned)(mask & 0xFFFEu));   // first argmax, j>=1

    if (lane == 0) {
      wrw[bN + r] = wr;
      jmp[bN + r] = bj;
    }
  }
}

// ---------------- Kernel D: jump-chain pooling via pointer doubling -------
__global__ __launch_bounds__(512) void k_chain(
    const void* __restrict__ x, const float* __restrict__ wrw,
    const float* __restrict__ srk, const int* __restrict__ jmp,
    const int* __restrict__ order, float* __restrict__ out)
{
  __shared__ int   tab[9][N_];   // f^(2^k) jump tables, sentinel 511
  __shared__ int   ol[N_];
  __shared__ float wl[N_];
  __shared__ float sl2[N_];
  __shared__ float cl[N_];       // coeff list in path order
  __shared__ int   rl[N_];       // row-id list
  __shared__ int   Pcnt;
  __shared__ int   s_mode;

  const int b = blockIdx.x, t = threadIdx.x;     // 512 threads
  if (t == 0) s_mode = detect16((const unsigned short*)x);

  ol[t] = order[b * N_ + t];
  if (t < RES_) {
    wl[t]  = wrw[b * N_ + t];
    sl2[t] = srk[b * N_ + t];
    tab[0][t] = min(t + jmp[b * N_ + t], RES_);
  } else {
    tab[0][t] = RES_;
  }
  if (t == 0) Pcnt = RES_;
  __syncthreads();
  const int mode_x = s_mode;
#pragma unroll
  for (int k = 1; k < 9; ++k) {
    int v = tab[k - 1][tab[k - 1][t]];
    tab[k][t] = v;
    __syncthreads();
  }
  int node = 0;
#pragma unroll
  for (int k = 0; k < 9; ++k)
    if ((t >> k) & 1) node = tab[k][node];
  bool valid = (node < RES_);
  cl[t] = valid ? wl[node] * sl2[node] : 0.0f;
  rl[t] = valid ? ol[node] : 0;
  if (!valid) atomicMin(&Pcnt, t);
  __syncthreads();

  if (t < C_) {
    const int P = Pcnt;
    float acc = 0.f;
    int i = 0;
    for (; i + 4 <= P; i += 4) {
      float c0 = cl[i],     c1 = cl[i + 1], c2 = cl[i + 2], c3 = cl[i + 3];
      int   r0 = rl[i],     r1 = rl[i + 1], r2 = rl[i + 2], r3 = rl[i + 3];
      float x0 = ld1(x, (b * N_ + r0) * C_ + t, mode_x);
      float x1 = ld1(x, (b * N_ + r1) * C_ + t, mode_x);
      float x2 = ld1(x, (b * N_ + r2) * C_ + t, mode_x);
      float x3 = ld1(x, (b * N_ + r3) * C_ + t, mode_x);
      acc = acc + c0 * x0;                       // exact reference order
      acc = acc + c1 * x1;
      acc = acc + c2 * x2;
      acc = acc + c3 * x3;
    }
    for (; i < P; ++i)
      acc = acc + cl[i] * ld1(x, (b * N_ + rl[i]) * C_ + t, mode_x);
    out[b * C_ + t] = acc;
  }
}

extern "C" void kernel_launch(void* const* d_in, const int* in_sizes, int n_in,
                              void* d_out, int out_size, void* d_ws, size_t ws_size,
                              hipStream_t stream) {
  const void* x = nullptr; const void* w = nullptr; const void* a = nullptr;
  const int* ep = nullptr;
  for (int i = 0; i < n_in; ++i) {
    int s = in_sizes[i];
    if      (s == B_ * N_ * C_) x  = d_in[i];
    else if (s == C_)           w  = d_in[i];
    else if (s == 2 * C_)       a  = d_in[i];
    else if (s == 1)            ep = (const int*)d_in[i];
  }
  if (!x)  x  = d_in[0];
  if (!w)  w  = d_in[2];
  if (!a)  a  = d_in[3];
  if (!ep) ep = (const int*)d_in[4];
  (void)out_size; (void)ws_size;

  float* ws = (float*)d_ws;
  const int NN = B_ * N_;              // 32768
  float* sc    = ws;                   // NN
  float* asr   = ws + NN;              // NN
  float* ads   = ws + 2 * NN;          // NN
  int*   order = (int*)(ws + 3 * NN);  // NN
  float* srk   = ws + 4 * NN;          // NN
  float* wrw   = ws + 5 * NN;          // NN
  int*   jmp   = (int*)(ws + 6 * NN);  // NN

  k_scores<<<NN / 4, 256, 0, stream>>>(x, w, a, sc, asr, ads);
  k_sort<<<B_, N_, 0, stream>>>(sc, order, srk);
  k_att<<<B_ * 8, 256, 0, stream>>>(x, asr, ads, order, ep, wrw, jmp);
  k_chain<<<B_, N_, 0, stream>>>(x, wrw, srk, jmp, order, (float*)d_out);
}